// Round 2
// baseline (588.580 us; speedup 1.0000x reference)
//
#include <hip/hip_runtime.h>

typedef __attribute__((ext_vector_type(8))) _Float16 f16x8;
typedef __attribute__((ext_vector_type(4))) _Float16 f16x4;
typedef __attribute__((ext_vector_type(4))) float f32x4;
typedef _Float16 half_t;

#define MFMA16(a, b, c) __builtin_amdgcn_mfma_f32_16x16x32_f16((a), (b), (c), 0, 0, 0)

// B=4, S=4096, D=256 fixed for this problem.

// ---------------- projection: out[s][e] = sum_d X[s][d]*W[e][d] + bias[e], fp16 out ----
__global__ __launch_bounds__(512, 2)
void proj_kernel(const float* __restrict__ X, const float* __restrict__ W,
                 const float* __restrict__ bias, half_t* __restrict__ out)
{
    __shared__ half_t Wl[256 * 264];   // padded stride 264 (528B) -> ~2-way banks
    int tid = threadIdx.x;
    for (int i = 0; i < 128; ++i) {    // 512 thr * 128 = 65536 elements
        int idx = tid + i * 512;
        int r = idx >> 8, c = idx & 255;
        Wl[r * 264 + c] = (half_t)W[idx];
    }
    __syncthreads();

    int w = tid >> 6, lane = tid & 63, l15 = lane & 15, hi = lane >> 4;
    int row0 = blockIdx.x * 128 + w * 16;   // 128 blocks * 128 rows = 16384 rows

    const float* xb = X + (size_t)(row0 + l15) * 256 + hi * 8;
    f32x4 acc[16];
#pragma unroll
    for (int n = 0; n < 16; ++n) acc[n] = (f32x4){0.f, 0.f, 0.f, 0.f};

#pragma unroll
    for (int kd = 0; kd < 8; ++kd) {
        const float4* xv = (const float4*)(xb + kd * 32);
        float4 x0 = xv[0], x1 = xv[1];
        f16x8 a = { (half_t)x0.x, (half_t)x0.y, (half_t)x0.z, (half_t)x0.w,
                    (half_t)x1.x, (half_t)x1.y, (half_t)x1.z, (half_t)x1.w };
#pragma unroll
        for (int n = 0; n < 16; ++n) {
            f16x8 bf = *(const f16x8*)&Wl[(n * 16 + l15) * 264 + kd * 32 + hi * 8];
            acc[n] = MFMA16(a, bf, acc[n]);
        }
    }

#pragma unroll
    for (int n = 0; n < 16; ++n) {
        float bv = bias[n * 16 + l15];
#pragma unroll
        for (int r = 0; r < 4; ++r) {
            float v = acc[n][r] + bv;
            out[(size_t)(row0 + 4 * hi + r) * 256 + n * 16 + l15] = (half_t)v;
        }
    }
}

// ---------------- V transpose: vt[b][d][s] = (fp16) V[b][s][d] ----------------
__global__ __launch_bounds__(256)
void vt_kernel(const float* __restrict__ V, half_t* __restrict__ vt)
{
    __shared__ half_t tile[64][65];
    int tid = threadIdx.x;
    int b = blockIdx.x >> 8, rest = blockIdx.x & 255;
    int s0 = (rest >> 2) * 64, d0 = (rest & 3) * 64;
#pragma unroll
    for (int i = 0; i < 16; ++i) {
        int srow = i * 4 + (tid >> 6);
        int dcol = tid & 63;
        tile[srow][dcol] = (half_t)V[(size_t)(b * 4096 + s0 + srow) * 256 + d0 + dcol];
    }
    __syncthreads();
#pragma unroll
    for (int i = 0; i < 16; ++i) {
        int drow = i * 4 + (tid >> 6);
        int scol = tid & 63;
        vt[(size_t)(b * 256 + d0 + drow) * 4096 + s0 + scol] = tile[scol][drow];
    }
}

// ---------------- fused attention: 16 q-rows/block, 16 waves x 256 k-cols ------------
// Swapped QK^T (mfma(K,Q)): lane (l15,hi) holds S[q=l15][k = w*256 + ct*16 + 4*hi + r]
__global__ __launch_bounds__(1024, 4)
void attn_kernel(const half_t* __restrict__ qh, const half_t* __restrict__ kh,
                 const half_t* __restrict__ vt, const int* __restrict__ mask,
                 float* __restrict__ ctx_out, float* __restrict__ attn_out)
{
    __shared__ half_t stash[16][4096];      // 128 KiB: per-wave 16x256 fp16 P slice
    __shared__ float redbuf[2][16][16];     // [max|sum][wave][q-row]

    const int tid = threadIdx.x;
    const int w = tid >> 6, lane = tid & 63, l15 = lane & 15, hi = lane >> 4;
    const int bid = blockIdx.x;
    const int wgid = (bid & 7) * 128 + (bid >> 3);   // XCD-contiguous q-tiles
    const int b = wgid >> 8, qt = wgid & 255, q0 = qt * 16;

    // Q B-fragments: col=l15 -> q-row q0+l15, k(d) = hi*8+j
    f16x8 qf[8];
    const half_t* qb = qh + ((size_t)(b * 4096 + q0 + l15)) * 256 + hi * 8;
#pragma unroll
    for (int kd = 0; kd < 8; ++kd) qf[kd] = *(const f16x8*)(qb + kd * 32);

    // ---- QK^T swapped: wave w covers k-cols [w*256, w*256+256) ----
    f32x4 sc[16];
    const half_t* kbase = kh + ((size_t)(b * 4096 + w * 256 + l15)) * 256 + hi * 8;
#pragma unroll
    for (int ct = 0; ct < 16; ++ct) {
        f32x4 c = {0.f, 0.f, 0.f, 0.f};
        const half_t* kb = kbase + (size_t)ct * 16 * 256;
#pragma unroll
        for (int kd = 0; kd < 8; ++kd) {
            f16x8 kf = *(const f16x8*)(kb + kd * 32);
            c = MFMA16(kf, qf[kd], c);
        }
        sc[ct] = c * 0.0625f;   // 1/sqrt(256)
    }

    // ---- mask: per-lane q-row; masked row -> all 0 -> uniform softmax ----
    const bool km = mask[b * 4096 + q0 + l15] != 0;
    if (!km) {
#pragma unroll
        for (int ct = 0; ct < 16; ++ct) sc[ct] = (f32x4){0.f, 0.f, 0.f, 0.f};
    }

    // ---- row max: lane-local 64 vals -> xor16/32 -> cross-wave via LDS ----
    float vmax = sc[0][0];
#pragma unroll
    for (int ct = 0; ct < 16; ++ct)
#pragma unroll
        for (int r = 0; r < 4; ++r) vmax = fmaxf(vmax, sc[ct][r]);
    vmax = fmaxf(vmax, __shfl_xor(vmax, 16, 64));
    vmax = fmaxf(vmax, __shfl_xor(vmax, 32, 64));
    if (lane < 16) redbuf[0][w][l15] = vmax;
    __syncthreads();
    float m = redbuf[0][0][l15];
#pragma unroll
    for (int ww = 1; ww < 16; ++ww) m = fmaxf(m, redbuf[0][ww][l15]);

    // ---- exp + row sum ----
    float vsum = 0.f;
#pragma unroll
    for (int ct = 0; ct < 16; ++ct)
#pragma unroll
        for (int r = 0; r < 4; ++r) {
            float p = __expf(sc[ct][r] - m);
            sc[ct][r] = p;
            vsum += p;
        }
    vsum += __shfl_xor(vsum, 16, 64);
    vsum += __shfl_xor(vsum, 32, 64);
    if (lane < 16) redbuf[1][w][l15] = vsum;
    __syncthreads();
    float ssum = 0.f;
#pragma unroll
    for (int ww = 0; ww < 16; ++ww) ssum += redbuf[1][ww][l15];
    const float inv = 1.0f / ssum;

    // ---- normalize: attn f32 float4 store + fp16 stash (XOR-swizzled rows) ----
    float* aout = attn_out + ((size_t)(b * 4096 + q0 + l15)) * 4096 + w * 256;
    char* sw = (char*)&stash[w][0];
    const int swz = (l15 & 7) << 4;
#pragma unroll
    for (int ct = 0; ct < 16; ++ct) {
        f32x4 a = sc[ct] * inv;
        *(f32x4*)(aout + ct * 16 + 4 * hi) = a;
        f16x4 hv = { (half_t)a[0], (half_t)a[1], (half_t)a[2], (half_t)a[3] };
        *(f16x4*)(sw + ((l15 * 512 + ct * 32 + hi * 8) ^ swz)) = hv;
    }

    // ---- PV: ctx partial [16 x 256] per wave over its 256 k-cols ----
    f32x4 acc[16];
#pragma unroll
    for (int n = 0; n < 16; ++n) acc[n] = (f32x4){0.f, 0.f, 0.f, 0.f};
    const half_t* vtb = vt + ((size_t)(b * 256 + l15)) * 4096 + w * 256 + hi * 8;
#pragma unroll
    for (int kd = 0; kd < 8; ++kd) {
        f16x8 af = *(const f16x8*)(sw + ((l15 * 512 + kd * 64 + hi * 16) ^ swz));
        const half_t* vb = vtb + kd * 32;
#pragma unroll
        for (int n = 0; n < 16; ++n) {
            f16x8 vf = *(const f16x8*)(vb + (size_t)n * 16 * 4096);
            acc[n] = MFMA16(af, vf, acc[n]);
        }
    }

    // ---- cross-wave ctx reduce: 4 slices x 4 sequential rounds (overlay stash) ----
    __syncthreads();
    float* slices = (float*)&stash[0][0];   // 4 slices of 4096 f32 (16 KiB each)
    const int g = w & 3, ord = w >> 2;
    for (int rnd = 0; rnd < 4; ++rnd) {
        if (ord == rnd) {
            float* S = slices + g * 4096;
#pragma unroll
            for (int n = 0; n < 16; ++n)
#pragma unroll
                for (int rr = 0; rr < 4; ++rr) {
                    int idx = (4 * hi + rr) * 256 + n * 16 + l15;
                    if (rnd == 0) S[idx] = acc[n][rr];
                    else         S[idx] += acc[n][rr];
                }
        }
        __syncthreads();
    }

    // ---- cooperative coalesced ctx write ----
    const int idx4 = tid * 4;
    f32x4 s0 = *(const f32x4*)(slices + idx4);
    f32x4 s1 = *(const f32x4*)(slices + 4096 + idx4);
    f32x4 s2 = *(const f32x4*)(slices + 8192 + idx4);
    f32x4 s3 = *(const f32x4*)(slices + 12288 + idx4);
    f32x4 rsum = (s0 + s1) + (s2 + s3);
    *(f32x4*)(ctx_out + ((size_t)(b * 4096) + q0) * 256 + idx4) = rsum;
}

extern "C" void kernel_launch(void* const* d_in, const int* in_sizes, int n_in,
                              void* d_out, int out_size, void* d_ws, size_t ws_size,
                              hipStream_t stream) {
    const float* query = (const float*)d_in[0];
    const float* key   = (const float*)d_in[1];
    const float* value = (const float*)d_in[2];
    const int*   mask  = (const int*)d_in[3];
    const float* Wq    = (const float*)d_in[4];
    const float* bq    = (const float*)d_in[5];
    const float* Wk    = (const float*)d_in[6];
    const float* bk    = (const float*)d_in[7];

    float* ctx  = (float*)d_out;                       // [4,4096,256]
    float* attn = ctx + (size_t)4 * 4096 * 256;        // [4,4096,4096]

    half_t* qh = (half_t*)d_ws;                        // 8 MB
    half_t* kh = qh + (size_t)4 * 4096 * 256;          // 8 MB
    half_t* vt = kh + (size_t)4 * 4096 * 256;          // 8 MB

    proj_kernel<<<128, 512, 0, stream>>>(query, Wq, bq, qh);
    proj_kernel<<<128, 512, 0, stream>>>(key,   Wk, bk, kh);
    vt_kernel<<<1024, 256, 0, stream>>>(value, vt);
    attn_kernel<<<1024, 1024, 0, stream>>>(qh, kh, vt, mask, ctx, attn);
}

// Round 3
// 587.774 us; speedup vs baseline: 1.0014x; 1.0014x over previous
//
#include <hip/hip_runtime.h>

typedef __attribute__((ext_vector_type(8))) _Float16 f16x8;
typedef __attribute__((ext_vector_type(4))) _Float16 f16x4;
typedef __attribute__((ext_vector_type(4))) float f32x4;
typedef _Float16 half_t;

#define MFMA16(a, b, c) __builtin_amdgcn_mfma_f32_16x16x32_f16((a), (b), (c), 0, 0, 0)

// B=4, S=4096, D=256 fixed for this problem.

// ---------------- projection: out[s][e] = sum_d X[s][d]*W[e][d] + bias[e], fp16 out ----
__global__ __launch_bounds__(512, 2)
void proj_kernel(const float* __restrict__ X, const float* __restrict__ W,
                 const float* __restrict__ bias, half_t* __restrict__ out)
{
    __shared__ half_t Wl[256 * 264];   // padded stride 264 (528B) -> ~2-way banks
    int tid = threadIdx.x;
    for (int i = 0; i < 128; ++i) {    // 512 thr * 128 = 65536 elements
        int idx = tid + i * 512;
        int r = idx >> 8, c = idx & 255;
        Wl[r * 264 + c] = (half_t)W[idx];
    }
    __syncthreads();

    int w = tid >> 6, lane = tid & 63, l15 = lane & 15, hi = lane >> 4;
    int row0 = blockIdx.x * 128 + w * 16;   // 128 blocks * 128 rows = 16384 rows

    const float* xb = X + (size_t)(row0 + l15) * 256 + hi * 8;
    f32x4 acc[16];
#pragma unroll
    for (int n = 0; n < 16; ++n) acc[n] = (f32x4){0.f, 0.f, 0.f, 0.f};

#pragma unroll
    for (int kd = 0; kd < 8; ++kd) {
        const float4* xv = (const float4*)(xb + kd * 32);
        float4 x0 = xv[0], x1 = xv[1];
        f16x8 a = { (half_t)x0.x, (half_t)x0.y, (half_t)x0.z, (half_t)x0.w,
                    (half_t)x1.x, (half_t)x1.y, (half_t)x1.z, (half_t)x1.w };
#pragma unroll
        for (int n = 0; n < 16; ++n) {
            f16x8 bf = *(const f16x8*)&Wl[(n * 16 + l15) * 264 + kd * 32 + hi * 8];
            acc[n] = MFMA16(a, bf, acc[n]);
        }
    }

#pragma unroll
    for (int n = 0; n < 16; ++n) {
        float bv = bias[n * 16 + l15];
#pragma unroll
        for (int r = 0; r < 4; ++r) {
            float v = acc[n][r] + bv;
            out[(size_t)(row0 + 4 * hi + r) * 256 + n * 16 + l15] = (half_t)v;
        }
    }
}

// ---------------- V transpose: vt[b][d][s] = (fp16) V[b][s][d] ----------------
__global__ __launch_bounds__(256)
void vt_kernel(const float* __restrict__ V, half_t* __restrict__ vt)
{
    __shared__ half_t tile[64][65];
    int tid = threadIdx.x;
    int b = blockIdx.x >> 8, rest = blockIdx.x & 255;
    int s0 = (rest >> 2) * 64, d0 = (rest & 3) * 64;
#pragma unroll
    for (int i = 0; i < 16; ++i) {
        int srow = i * 4 + (tid >> 6);
        int dcol = tid & 63;
        tile[srow][dcol] = (half_t)V[(size_t)(b * 4096 + s0 + srow) * 256 + d0 + dcol];
    }
    __syncthreads();
#pragma unroll
    for (int i = 0; i < 16; ++i) {
        int drow = i * 4 + (tid >> 6);
        int scol = tid & 63;
        vt[(size_t)(b * 256 + d0 + drow) * 4096 + s0 + scol] = tile[scol][drow];
    }
}

// ---------------- fused attention: 16 q-rows/block, 16 waves x 256 k-cols ------------
// Swapped QK^T (mfma(K,Q)): lane (l15,hi) holds S[q=l15][k = w*256 + ct*16 + 4*hi + r]
__global__ __launch_bounds__(1024, 4)
void attn_kernel(const half_t* __restrict__ qh, const half_t* __restrict__ kh,
                 const half_t* __restrict__ vt, const int* __restrict__ mask,
                 float* __restrict__ ctx_out, float* __restrict__ attn_out)
{
    __shared__ half_t stash[16][4096];      // 128 KiB: per-wave 16x256 fp16 P slice
    __shared__ float redbuf[2][16][16];     // [max|sum][wave][q-row]

    const int tid = threadIdx.x;
    const int w = tid >> 6, lane = tid & 63, l15 = lane & 15, hi = lane >> 4;
    const int bid = blockIdx.x;
    const int wgid = (bid & 7) * 128 + (bid >> 3);   // XCD-contiguous q-tiles
    const int b = wgid >> 8, qt = wgid & 255, q0 = qt * 16;

    // Q B-fragments: col=l15 -> q-row q0+l15, k(d) = hi*8+j
    f16x8 qf[8];
    const half_t* qb = qh + ((size_t)(b * 4096 + q0 + l15)) * 256 + hi * 8;
#pragma unroll
    for (int kd = 0; kd < 8; ++kd) qf[kd] = *(const f16x8*)(qb + kd * 32);

    // ---- QK^T swapped: wave w covers k-cols [w*256, w*256+256) ----
    f32x4 sc[16];
    const half_t* kbase = kh + ((size_t)(b * 4096 + w * 256 + l15)) * 256 + hi * 8;
#pragma unroll
    for (int ct = 0; ct < 16; ++ct) {
        f32x4 c = {0.f, 0.f, 0.f, 0.f};
        const half_t* kb = kbase + (size_t)ct * 16 * 256;
#pragma unroll
        for (int kd = 0; kd < 8; ++kd) {
            f16x8 kf = *(const f16x8*)(kb + kd * 32);
            c = MFMA16(kf, qf[kd], c);
        }
        sc[ct] = c * 0.0625f;   // 1/sqrt(256)
    }

    // ---- mask: per-lane q-row; masked row -> all 0 -> uniform softmax ----
    const bool km = mask[b * 4096 + q0 + l15] != 0;
    if (!km) {
#pragma unroll
        for (int ct = 0; ct < 16; ++ct) sc[ct] = (f32x4){0.f, 0.f, 0.f, 0.f};
    }

    // ---- row max: lane-local 64 vals -> xor16/32 -> cross-wave via LDS ----
    float vmax = sc[0][0];
#pragma unroll
    for (int ct = 0; ct < 16; ++ct)
#pragma unroll
        for (int r = 0; r < 4; ++r) vmax = fmaxf(vmax, sc[ct][r]);
    vmax = fmaxf(vmax, __shfl_xor(vmax, 16, 64));
    vmax = fmaxf(vmax, __shfl_xor(vmax, 32, 64));
    if (lane < 16) redbuf[0][w][l15] = vmax;
    __syncthreads();
    float m = redbuf[0][0][l15];
#pragma unroll
    for (int ww = 1; ww < 16; ++ww) m = fmaxf(m, redbuf[0][ww][l15]);

    // ---- exp + row sum ----
    float vsum = 0.f;
#pragma unroll
    for (int ct = 0; ct < 16; ++ct)
#pragma unroll
        for (int r = 0; r < 4; ++r) {
            float p = __expf(sc[ct][r] - m);
            sc[ct][r] = p;
            vsum += p;
        }
    vsum += __shfl_xor(vsum, 16, 64);
    vsum += __shfl_xor(vsum, 32, 64);
    if (lane < 16) redbuf[1][w][l15] = vsum;
    __syncthreads();
    float ssum = 0.f;
#pragma unroll
    for (int ww = 0; ww < 16; ++ww) ssum += redbuf[1][ww][l15];
    const float inv = 1.0f / ssum;

    // ---- normalize: attn f32 float4 store + fp16 stash (XOR-swizzled rows) ----
    float* aout = attn_out + ((size_t)(b * 4096 + q0 + l15)) * 4096 + w * 256;
    char* sw = (char*)&stash[w][0];
    const int swz = (l15 & 7) << 4;
#pragma unroll
    for (int ct = 0; ct < 16; ++ct) {
        f32x4 a = sc[ct] * inv;
        *(f32x4*)(aout + ct * 16 + 4 * hi) = a;
        f16x4 hv = { (half_t)a[0], (half_t)a[1], (half_t)a[2], (half_t)a[3] };
        *(f16x4*)(sw + ((l15 * 512 + ct * 32 + hi * 8) ^ swz)) = hv;
    }

    // ---- PV: ctx partial [16 x 256] per wave over its 256 k-cols ----
    f32x4 acc[16];
#pragma unroll
    for (int n = 0; n < 16; ++n) acc[n] = (f32x4){0.f, 0.f, 0.f, 0.f};
    const half_t* vtb = vt + ((size_t)(b * 256 + l15)) * 4096 + w * 256 + hi * 8;
#pragma unroll
    for (int kd = 0; kd < 8; ++kd) {
        f16x8 af = *(const f16x8*)(sw + ((l15 * 512 + kd * 64 + hi * 16) ^ swz));
        const half_t* vb = vtb + kd * 32;
#pragma unroll
        for (int n = 0; n < 16; ++n) {
            f16x8 vf = *(const f16x8*)(vb + (size_t)n * 16 * 4096);
            acc[n] = MFMA16(af, vf, acc[n]);
        }
    }

    // ---- cross-wave ctx reduce: 4 slices x 4 sequential rounds (overlay stash) ----
    __syncthreads();
    float* slices = (float*)&stash[0][0];   // 4 slices of 4096 f32 (16 KiB each)
    const int g = w & 3, ord = w >> 2;
    for (int rnd = 0; rnd < 4; ++rnd) {
        if (ord == rnd) {
            float* S = slices + g * 4096;
#pragma unroll
            for (int n = 0; n < 16; ++n)
#pragma unroll
                for (int rr = 0; rr < 4; ++rr) {
                    int idx = (4 * hi + rr) * 256 + n * 16 + l15;
                    if (rnd == 0) S[idx] = acc[n][rr];
                    else         S[idx] += acc[n][rr];
                }
        }
        __syncthreads();
    }

    // ---- cooperative coalesced ctx write ----
    const int idx4 = tid * 4;
    f32x4 s0 = *(const f32x4*)(slices + idx4);
    f32x4 s1 = *(const f32x4*)(slices + 4096 + idx4);
    f32x4 s2 = *(const f32x4*)(slices + 8192 + idx4);
    f32x4 s3 = *(const f32x4*)(slices + 12288 + idx4);
    f32x4 rsum = (s0 + s1) + (s2 + s3);
    *(f32x4*)(ctx_out + ((size_t)(b * 4096) + q0) * 256 + idx4) = rsum;
}

extern "C" void kernel_launch(void* const* d_in, const int* in_sizes, int n_in,
                              void* d_out, int out_size, void* d_ws, size_t ws_size,
                              hipStream_t stream) {
    const float* query = (const float*)d_in[0];
    const float* key   = (const float*)d_in[1];
    const float* value = (const float*)d_in[2];
    const int*   mask  = (const int*)d_in[3];
    const float* Wq    = (const float*)d_in[4];
    const float* bq    = (const float*)d_in[5];
    const float* Wk    = (const float*)d_in[6];
    const float* bk    = (const float*)d_in[7];

    float* ctx  = (float*)d_out;                       // [4,4096,256]
    float* attn = ctx + (size_t)4 * 4096 * 256;        // [4,4096,4096]

    half_t* qh = (half_t*)d_ws;                        // 8 MB
    half_t* kh = qh + (size_t)4 * 4096 * 256;          // 8 MB
    half_t* vt = kh + (size_t)4 * 4096 * 256;          // 8 MB

    proj_kernel<<<128, 512, 0, stream>>>(query, Wq, bq, qh);
    proj_kernel<<<128, 512, 0, stream>>>(key,   Wk, bk, kh);
    vt_kernel<<<1024, 256, 0, stream>>>(value, vt);
    attn_kernel<<<1024, 1024, 0, stream>>>(qh, kh, vt, mask, ctx, attn);
}

// Round 4
// 585.290 us; speedup vs baseline: 1.0056x; 1.0042x over previous
//
#include <hip/hip_runtime.h>

typedef __attribute__((ext_vector_type(8))) _Float16 f16x8;
typedef __attribute__((ext_vector_type(4))) _Float16 f16x4;
typedef __attribute__((ext_vector_type(4))) float f32x4;
typedef _Float16 half_t;

#define MFMA16(a, b, c) __builtin_amdgcn_mfma_f32_16x16x32_f16((a), (b), (c), 0, 0, 0)

// B=4, S=4096, D=256 fixed for this problem.

// ---------------- projection: out[s][e] = sum_d X[s][d]*W[e][d] + bias[e], fp16 out ----
__global__ __launch_bounds__(512, 2)
void proj_kernel(const float* __restrict__ X, const float* __restrict__ W,
                 const float* __restrict__ bias, half_t* __restrict__ out)
{
    __shared__ half_t Wl[256 * 264];   // padded stride 264 (528B) -> ~2-way banks
    int tid = threadIdx.x;
    for (int i = 0; i < 128; ++i) {    // 512 thr * 128 = 65536 elements
        int idx = tid + i * 512;
        int r = idx >> 8, c = idx & 255;
        Wl[r * 264 + c] = (half_t)W[idx];
    }
    __syncthreads();

    int w = tid >> 6, lane = tid & 63, l15 = lane & 15, hi = lane >> 4;
    int row0 = blockIdx.x * 128 + w * 16;   // 128 blocks * 128 rows = 16384 rows

    const float* xb = X + (size_t)(row0 + l15) * 256 + hi * 8;
    f32x4 acc[16];
#pragma unroll
    for (int n = 0; n < 16; ++n) acc[n] = (f32x4){0.f, 0.f, 0.f, 0.f};

#pragma unroll
    for (int kd = 0; kd < 8; ++kd) {
        const float4* xv = (const float4*)(xb + kd * 32);
        float4 x0 = xv[0], x1 = xv[1];
        f16x8 a = { (half_t)x0.x, (half_t)x0.y, (half_t)x0.z, (half_t)x0.w,
                    (half_t)x1.x, (half_t)x1.y, (half_t)x1.z, (half_t)x1.w };
#pragma unroll
        for (int n = 0; n < 16; ++n) {
            f16x8 bf = *(const f16x8*)&Wl[(n * 16 + l15) * 264 + kd * 32 + hi * 8];
            acc[n] = MFMA16(a, bf, acc[n]);
        }
    }

#pragma unroll
    for (int n = 0; n < 16; ++n) {
        float bv = bias[n * 16 + l15];
#pragma unroll
        for (int r = 0; r < 4; ++r) {
            float v = acc[n][r] + bv;
            out[(size_t)(row0 + 4 * hi + r) * 256 + n * 16 + l15] = (half_t)v;
        }
    }
}

// ---------------- V transpose: vt[b][d][s] = (fp16) V[b][s][d] ----------------
__global__ __launch_bounds__(256)
void vt_kernel(const float* __restrict__ V, half_t* __restrict__ vt)
{
    __shared__ half_t tile[64][65];
    int tid = threadIdx.x;
    int b = blockIdx.x >> 8, rest = blockIdx.x & 255;
    int s0 = (rest >> 2) * 64, d0 = (rest & 3) * 64;
#pragma unroll
    for (int i = 0; i < 16; ++i) {
        int srow = i * 4 + (tid >> 6);
        int dcol = tid & 63;
        tile[srow][dcol] = (half_t)V[(size_t)(b * 4096 + s0 + srow) * 256 + d0 + dcol];
    }
    __syncthreads();
#pragma unroll
    for (int i = 0; i < 16; ++i) {
        int drow = i * 4 + (tid >> 6);
        int scol = tid & 63;
        vt[(size_t)(b * 256 + d0 + drow) * 4096 + s0 + scol] = tile[scol][drow];
    }
}

// ---------------- fused attention: 16 q-rows/block, 16 waves x 256 k-cols ------------
// Swapped QK^T (mfma(K,Q)): lane (l15,hi) holds S[q=l15][k = w*256 + ct*16 + 4*hi + r]
__global__ __launch_bounds__(1024, 4)
void attn_kernel(const half_t* __restrict__ qh, const half_t* __restrict__ kh,
                 const half_t* __restrict__ vt, const int* __restrict__ mask,
                 float* __restrict__ ctx_out, float* __restrict__ attn_out)
{
    __shared__ half_t stash[16][4096];      // 128 KiB: per-wave 16x256 fp16 P slice
    __shared__ float redbuf[2][16][16];     // [max|sum][wave][q-row]

    const int tid = threadIdx.x;
    const int w = tid >> 6, lane = tid & 63, l15 = lane & 15, hi = lane >> 4;
    const int bid = blockIdx.x;
    const int wgid = (bid & 7) * 128 + (bid >> 3);   // XCD-contiguous q-tiles
    const int b = wgid >> 8, qt = wgid & 255, q0 = qt * 16;

    // Q B-fragments: col=l15 -> q-row q0+l15, k(d) = hi*8+j
    f16x8 qf[8];
    const half_t* qb = qh + ((size_t)(b * 4096 + q0 + l15)) * 256 + hi * 8;
#pragma unroll
    for (int kd = 0; kd < 8; ++kd) qf[kd] = *(const f16x8*)(qb + kd * 32);

    // ---- QK^T swapped: wave w covers k-cols [w*256, w*256+256) ----
    f32x4 sc[16];
    const half_t* kbase = kh + ((size_t)(b * 4096 + w * 256 + l15)) * 256 + hi * 8;
#pragma unroll
    for (int ct = 0; ct < 16; ++ct) {
        f32x4 c = {0.f, 0.f, 0.f, 0.f};
        const half_t* kb = kbase + (size_t)ct * 16 * 256;
#pragma unroll
        for (int kd = 0; kd < 8; ++kd) {
            f16x8 kf = *(const f16x8*)(kb + kd * 32);
            c = MFMA16(kf, qf[kd], c);
        }
        sc[ct] = c * 0.0625f;   // 1/sqrt(256)
    }

    // ---- mask: per-lane q-row; masked row -> all 0 -> uniform softmax ----
    const bool km = mask[b * 4096 + q0 + l15] != 0;
    if (!km) {
#pragma unroll
        for (int ct = 0; ct < 16; ++ct) sc[ct] = (f32x4){0.f, 0.f, 0.f, 0.f};
    }

    // ---- row max: lane-local 64 vals -> xor16/32 -> cross-wave via LDS ----
    float vmax = sc[0][0];
#pragma unroll
    for (int ct = 0; ct < 16; ++ct)
#pragma unroll
        for (int r = 0; r < 4; ++r) vmax = fmaxf(vmax, sc[ct][r]);
    vmax = fmaxf(vmax, __shfl_xor(vmax, 16, 64));
    vmax = fmaxf(vmax, __shfl_xor(vmax, 32, 64));
    if (lane < 16) redbuf[0][w][l15] = vmax;
    __syncthreads();
    float m = redbuf[0][0][l15];
#pragma unroll
    for (int ww = 1; ww < 16; ++ww) m = fmaxf(m, redbuf[0][ww][l15]);

    // ---- exp + row sum ----
    float vsum = 0.f;
#pragma unroll
    for (int ct = 0; ct < 16; ++ct)
#pragma unroll
        for (int r = 0; r < 4; ++r) {
            float p = __expf(sc[ct][r] - m);
            sc[ct][r] = p;
            vsum += p;
        }
    vsum += __shfl_xor(vsum, 16, 64);
    vsum += __shfl_xor(vsum, 32, 64);
    if (lane < 16) redbuf[1][w][l15] = vsum;
    __syncthreads();
    float ssum = 0.f;
#pragma unroll
    for (int ww = 0; ww < 16; ++ww) ssum += redbuf[1][ww][l15];
    const float inv = 1.0f / ssum;

    // ---- normalize: attn f32 float4 store + fp16 stash (XOR-swizzled rows) ----
    float* aout = attn_out + ((size_t)(b * 4096 + q0 + l15)) * 4096 + w * 256;
    char* sw = (char*)&stash[w][0];
    const int swz = (l15 & 7) << 4;
#pragma unroll
    for (int ct = 0; ct < 16; ++ct) {
        f32x4 a = sc[ct] * inv;
        *(f32x4*)(aout + ct * 16 + 4 * hi) = a;
        f16x4 hv = { (half_t)a[0], (half_t)a[1], (half_t)a[2], (half_t)a[3] };
        *(f16x4*)(sw + ((l15 * 512 + ct * 32 + hi * 8) ^ swz)) = hv;
    }

    // ---- PV: ctx partial [16 x 256] per wave over its 256 k-cols ----
    f32x4 acc[16];
#pragma unroll
    for (int n = 0; n < 16; ++n) acc[n] = (f32x4){0.f, 0.f, 0.f, 0.f};
    const half_t* vtb = vt + ((size_t)(b * 256 + l15)) * 4096 + w * 256 + hi * 8;
#pragma unroll
    for (int kd = 0; kd < 8; ++kd) {
        f16x8 af = *(const f16x8*)(sw + ((l15 * 512 + kd * 64 + hi * 16) ^ swz));
        const half_t* vb = vtb + kd * 32;
#pragma unroll
        for (int n = 0; n < 16; ++n) {
            f16x8 vf = *(const f16x8*)(vb + (size_t)n * 16 * 4096);
            acc[n] = MFMA16(af, vf, acc[n]);
        }
    }

    // ---- cross-wave ctx reduce: 4 slices x 4 sequential rounds (overlay stash) ----
    __syncthreads();
    float* slices = (float*)&stash[0][0];   // 4 slices of 4096 f32 (16 KiB each)
    const int g = w & 3, ord = w >> 2;
    for (int rnd = 0; rnd < 4; ++rnd) {
        if (ord == rnd) {
            float* S = slices + g * 4096;
#pragma unroll
            for (int n = 0; n < 16; ++n)
#pragma unroll
                for (int rr = 0; rr < 4; ++rr) {
                    int idx = (4 * hi + rr) * 256 + n * 16 + l15;
                    if (rnd == 0) S[idx] = acc[n][rr];
                    else         S[idx] += acc[n][rr];
                }
        }
        __syncthreads();
    }

    // ---- cooperative coalesced ctx write ----
    const int idx4 = tid * 4;
    f32x4 s0 = *(const f32x4*)(slices + idx4);
    f32x4 s1 = *(const f32x4*)(slices + 4096 + idx4);
    f32x4 s2 = *(const f32x4*)(slices + 8192 + idx4);
    f32x4 s3 = *(const f32x4*)(slices + 12288 + idx4);
    f32x4 rsum = (s0 + s1) + (s2 + s3);
    *(f32x4*)(ctx_out + ((size_t)(b * 4096) + q0) * 256 + idx4) = rsum;
}

extern "C" void kernel_launch(void* const* d_in, const int* in_sizes, int n_in,
                              void* d_out, int out_size, void* d_ws, size_t ws_size,
                              hipStream_t stream) {
    const float* query = (const float*)d_in[0];
    const float* key   = (const float*)d_in[1];
    const float* value = (const float*)d_in[2];
    const int*   mask  = (const int*)d_in[3];
    const float* Wq    = (const float*)d_in[4];
    const float* bq    = (const float*)d_in[5];
    const float* Wk    = (const float*)d_in[6];
    const float* bk    = (const float*)d_in[7];

    float* ctx  = (float*)d_out;                       // [4,4096,256]
    float* attn = ctx + (size_t)4 * 4096 * 256;        // [4,4096,4096]

    half_t* qh = (half_t*)d_ws;                        // 8 MB
    half_t* kh = qh + (size_t)4 * 4096 * 256;          // 8 MB
    half_t* vt = kh + (size_t)4 * 4096 * 256;          // 8 MB

    proj_kernel<<<128, 512, 0, stream>>>(query, Wq, bq, qh);
    proj_kernel<<<128, 512, 0, stream>>>(key,   Wk, bk, kh);
    vt_kernel<<<1024, 256, 0, stream>>>(value, vt);
    attn_kernel<<<1024, 1024, 0, stream>>>(qh, kh, vt, mask, ctx, attn);
}